// Round 8
// baseline (419.849 us; speedup 1.0000x reference)
//
#include <hip/hip_runtime.h>

#define CH 256
#define HH 56
#define WW 56
#define HWSZ 3136
#define WQ_ELEMS (CH*CH*9)      // 589824

#define RGN 24576               // shorts per kh region (3 kw * 256 oc * 32 ic)
#define XT_OFF 2097152          // byte offset of x_t in ws
#define HP 58                   // padded h: hx+1, rows 0 and 57 are zeros

typedef short short8 __attribute__((ext_vector_type(8)));
typedef float f32x4 __attribute__((ext_vector_type(4)));
typedef __attribute__((address_space(3))) unsigned short as3_ushort;
typedef __attribute__((address_space(1))) const unsigned short as1_ushort;

__device__ __forceinline__ unsigned short f2bf(float f) {
  unsigned u = __builtin_bit_cast(unsigned, f);
  u += 0x7FFFu + ((u >> 16) & 1u);   // round-to-nearest-even
  return (unsigned short)(u >> 16);
}

// ---------------- kernel 1: max(|w|) ----------------
__global__ void absmax_kernel(const float4* __restrict__ w, unsigned* __restrict__ out) {
  int tid = blockIdx.x * 256 + threadIdx.x;
  float4 v = w[tid];
  float m = fmaxf(fmaxf(fabsf(v.x), fabsf(v.y)), fmaxf(fabsf(v.z), fabsf(v.w)));
  #pragma unroll
  for (int o = 32; o; o >>= 1) m = fmaxf(m, __shfl_xor(m, o, 64));
  if ((threadIdx.x & 63) == 0) atomicMax(out, __builtin_bit_cast(unsigned, m));
}

// ---------------- kernel 2: quantize -> bf16 (R6-verified layout) ----------------
// region (tap*8+t) of 8192 shorts; within: och*4096 + m*512 + l15*32 + kgp*8 + e,
// kgp = kg ^ ((l15>>2)&3)  (bank swizzle baked into global layout).
__global__ void quant_kernel(const float* __restrict__ w, const float* __restrict__ Wp,
                             const float* __restrict__ Wn, const unsigned* __restrict__ mx,
                             unsigned short* __restrict__ wq) {
  int o = blockIdx.x * 256 + threadIdx.x;
  int e   = o & 7;
  int kgp = (o >> 3) & 3;
  int l15 = (o >> 5) & 15;
  int m   = (o >> 9) & 7;
  int och = (o >> 12) & 1;
  int region = o >> 13;            // tap*8 + t
  int tap = region >> 3;
  int t   = region & 7;
  int kg  = kgp ^ ((l15 >> 2) & 3);
  int oc  = och * 128 + m * 16 + l15;
  int ic  = t * 32 + kg * 8 + e;
  float mv  = __builtin_bit_cast(float, *mx);
  float thr = 0.05f * mv;
  float v = w[(oc * CH + ic) * 9 + tap];
  float q = 0.f;
  if (mv > 0.f) {
    if (v > thr) q = Wp[0];
    else if (v < -thr) q = -Wn[0];
  }
  wq[o] = f2bf(q);
}

// ---------------- kernel 3: transpose+pad x -> x_t bf16 [n][58][64][256] ----------------
// hp = hx+1 (rows 0,57 zero); iw = xw+1 (cols 0, 57..63 zero). 128 ic per block.
__global__ __launch_bounds__(256)
void xpose_kernel(const float* __restrict__ x, unsigned short* __restrict__ xt) {
  const int n = blockIdx.x, hp = blockIdx.y, icb = blockIdx.z * 128;
  const int hx = hp - 1;
  const int lane = threadIdx.x & 63, wv = threadIdx.x >> 6;
  unsigned short* plane = xt + (((long)n * HP + hp) * 64) * 256 + icb;
  if ((unsigned)hx >= (unsigned)HH) {
    ushort2 z = {0, 0};
    #pragma unroll
    for (int i = 0; i < 16; ++i)
      *(ushort2*)&plane[(wv * 16 + i) * 256 + lane * 2] = z;
    return;
  }
  __shared__ unsigned short T[128][65];   // padded: read stride 130B -> 2-way free
  #pragma unroll 4
  for (int i = 0; i < 32; ++i) {
    int ic = wv * 32 + i;
    float v = (lane >= 1 && lane <= WW) ?
        x[(((long)n * CH + icb + ic) * HH + hx) * WW + (lane - 1)] : 0.f;
    T[ic][lane] = f2bf(v);
  }
  __syncthreads();
  #pragma unroll 4
  for (int i = 0; i < 16; ++i) {
    int iw = wv * 16 + i;
    ushort2 v = { T[lane * 2][iw], T[lane * 2 + 1][iw] };
    *(ushort2*)&plane[iw * 256 + lane * 2] = v;
  }
}

// ---------------- kernel 4: conv ----------------
// 512 thr, 8 waves = 2 och x 4 rows; wave tile 128oc x 64w. W in LDS (144KB,
// 3 kh regions, ring-staged via global_load_lds, counted vmcnt(6) drains).
// B (x) read from global x_t -> L1/L2 (separate pipe from LDS). No X staging.
__global__ __launch_bounds__(512, 1)
void conv_kernel(const unsigned short* __restrict__ wq, const unsigned short* __restrict__ xt,
                 const float* __restrict__ bias, float* __restrict__ out) {
  extern __shared__ unsigned short lds[];   // 3 * RGN shorts = 144KB

  const int tid  = threadIdx.x;
  const int lane = tid & 63;
  const int l15  = lane & 15;
  const int kg   = lane >> 4;
  const int wid  = tid >> 6;
  const int och  = wid & 1;
  const int wr   = wid >> 1;
  const int n    = blockIdx.x;
  const int h0   = blockIdx.y * 4;

  f32x4 acc[8][4];
  #pragma unroll
  for (int m = 0; m < 8; ++m)
    #pragma unroll
    for (int nc = 0; nc < 4; ++nc) acc[m][nc] = (f32x4)0.f;

  // A-read offset (matches quant layout's baked swizzle)
  const int aoff = och * 4096 + l15 * 32 + ((kg ^ ((l15 >> 2) & 3)) * 8);

  // B global offsets per (kw,nc): iw clamped (feeds only discarded w>=56)
  int iwoff[12];
  #pragma unroll
  for (int kw = 0; kw < 3; ++kw)
    #pragma unroll
    for (int nc = 0; nc < 4; ++nc) {
      int iw = nc * 16 + l15 + kw;
      if (iw > 63) iw = 63;
      iwoff[kw * 4 + nc] = iw * 256 + kg * 8;
    }

  // stage one kh region for ic-chunk t: exactly 6 gload_lds per wave
  auto stage = [&](int rgn, int t) {
    #pragma unroll
    for (int i = 0; i < 6; ++i) {
      const int g   = i * 8 + wid;       // 0..47
      const int kw  = g >> 4;
      const int sub = g & 15;
      const unsigned short* src = wq + ((rgn * 3 + kw) * 8 + t) * 8192 + sub * 512 + lane * 8;
      unsigned short* dst = lds + rgn * RGN + kw * 8192 + sub * 512;
      __builtin_amdgcn_global_load_lds((as1_ushort*)src, (as3_ushort*)dst, 16, 0, 0);
    }
  };

  // ---- prologue: regions 0,1 for t=0 ----
  stage(0, 0);
  stage(1, 0);
  asm volatile("s_waitcnt vmcnt(0)" ::: "memory");
  __builtin_amdgcn_s_barrier();
  __builtin_amdgcn_sched_barrier(0);

  const unsigned short* xbase = xt + ((long)n * HP) * 64 * 256;

  for (int t = 0; t < 8; ++t) {
    const unsigned short* xt_t = xbase + t * 32;
    #pragma unroll
    for (int p = 0; p < 3; ++p) {        // phase p reads region p (tap kh=p)
      // ring stage: p==0 -> region 2 for t; p==1/2 -> region p-1 for t+1
      bool staged = false;
      if (p == 0)              { stage(2, t);     staged = true; }
      else if (t < 7)          { stage(p - 1, t + 1); staged = true; }

      // B loads (global -> VGPR; slab is L1/L2-hot)
      const unsigned short* xr = xt_t + (long)(h0 + wr + p) * 64 * 256;
      short8 b[12];
      #pragma unroll
      for (int i = 0; i < 12; ++i) b[i] = *(const short8*)(xr + iwoff[i]);

      // A from LDS + MFMA
      #pragma unroll
      for (int kw = 0; kw < 3; ++kw) {
        const unsigned short* ap = lds + p * RGN + kw * 8192 + aoff;
        short8 a[8];
        #pragma unroll
        for (int m = 0; m < 8; ++m) a[m] = *(const short8*)(ap + m * 512);
        __builtin_amdgcn_s_setprio(1);
        #pragma unroll
        for (int m = 0; m < 8; ++m)
          #pragma unroll
          for (int nc = 0; nc < 4; ++nc)
            acc[m][nc] = __builtin_amdgcn_mfma_f32_16x16x32_bf16(a[m], b[kw * 4 + nc], acc[m][nc], 0, 0, 0);
        __builtin_amdgcn_s_setprio(0);
      }

      // drain previous phase's stage (1 phase of cover); keep this phase's 6 in flight
      if (staged) asm volatile("s_waitcnt vmcnt(6)" ::: "memory");
      else        asm volatile("s_waitcnt vmcnt(0)" ::: "memory");
      __builtin_amdgcn_s_barrier();
      __builtin_amdgcn_sched_barrier(0);
    }
  }

  // ---- epilogue: D col = l15 (w), row = kg*4 + j (oc) ----
  const int h = h0 + wr;
  #pragma unroll
  for (int m = 0; m < 8; ++m) {
    const int ocb = och * 128 + m * 16 + kg * 4;
    #pragma unroll
    for (int nc = 0; nc < 4; ++nc) {
      const int w = nc * 16 + l15;
      if (w < WW) {
        float* op = out + ((long)(n * CH + ocb) * HH + h) * WW + w;
        #pragma unroll
        for (int j = 0; j < 4; ++j)
          op[(long)j * HWSZ] = acc[m][nc][j] + bias[ocb + j];
      }
    }
  }
}

extern "C" void kernel_launch(void* const* d_in, const int* in_sizes, int n_in,
                              void* d_out, int out_size, void* d_ws, size_t ws_size,
                              hipStream_t stream) {
  const float* x      = (const float*)d_in[0];
  const float* weight = (const float*)d_in[1];
  const float* bias   = (const float*)d_in[2];
  const float* Wp     = (const float*)d_in[3];
  const float* Wn     = (const float*)d_in[4];
  float* out          = (float*)d_out;

  unsigned* mx        = (unsigned*)d_ws;
  unsigned short* wqp = (unsigned short*)((char*)d_ws + 64);
  unsigned short* xtp = (unsigned short*)((char*)d_ws + XT_OFF);   // 60.8 MB

  static const int LDS_BYTES = 3 * RGN * 2;   // 147456
  hipFuncSetAttribute((const void*)conv_kernel,
                      hipFuncAttributeMaxDynamicSharedMemorySize, LDS_BYTES);

  hipMemsetAsync(d_ws, 0, 64, stream);
  absmax_kernel<<<WQ_ELEMS / 4 / 256, 256, 0, stream>>>((const float4*)weight, mx);
  quant_kernel<<<WQ_ELEMS / 256, 256, 0, stream>>>(weight, Wp, Wn, mx, wqp);
  xpose_kernel<<<dim3(32, HP, 2), 256, 0, stream>>>(x, xtp);
  conv_kernel<<<dim3(32, HH / 4), 512, LDS_BYTES, stream>>>(wqp, xtp, bias, out);
}